// Round 9
// baseline (2147.395 us; speedup 1.0000x reference)
//
#include <hip/hip_runtime.h>
#include <stdint.h>

#define BATCH 512
#define TMAX 1024
#define DIN 4
#define H 64
#define NC 1098
#define GQ 16   // sequences per block (one MFMA N-tile); lengths sorted desc

typedef _Float16 f16;
typedef _Float16 f16x8 __attribute__((ext_vector_type(8)));
typedef float f32x4 __attribute__((ext_vector_type(4)));

#define MFMA16(a, b, c) __builtin_amdgcn_mfma_f32_16x16x32_f16((a), (b), (c), 0, 0, 0)

__device__ __forceinline__ float sigmoidf_(float x) {
    return 1.0f / (1.0f + __expf(-x));
}
__device__ __forceinline__ float tanhf_(float x) {
    return 1.0f - 2.0f / (__expf(2.0f * x) + 1.0f);
}
__device__ __forceinline__ f16x8 cvt8(float4 a, float4 b) {
    f16x8 r;
    r[0]=(f16)a.x; r[1]=(f16)a.y; r[2]=(f16)a.z; r[3]=(f16)a.w;
    r[4]=(f16)b.x; r[5]=(f16)b.y; r[6]=(f16)b.z; r[7]=(f16)b.w;
    return r;
}
__device__ __forceinline__ f16x8 zero8() {
    f16x8 r;
    #pragma unroll
    for (int z = 0; z < 8; z++) r[z] = (f16)0.f;
    return r;
}

// Fragment mappings used (HW-verified per guide):
//   A-frag: A[m = lane&15][k = quad*8 + j], 8 f16 per lane (4 VGPR)
//   B-frag: Bt[n = lane&15][k = quad*8 + j]   (i.e. per-seq column vector)
//   C/D:    D[m = quad*4 + reg][n = lane&15]
// Gate rows interleaved: R = 4*j + gate  =>  for lane (q,n), M-tile mt:
//   D rows are j = 4*mt + q, gates = reg 0..3  -> one lane holds (i,f,g,o)
//   of one h-index, so the c/h update is pure per-lane VALU. Source weight
//   row for R: sr = (R&3)*64 + (R>>2)  (PyTorch gate-major storage).

// ================= Layer 0: MFMA over 16-seq groups, K = 64(h)+4(x) =========
__global__ __launch_bounds__(256) void lstm0_mfma(
    const float* __restrict__ x, const int* __restrict__ lengths,
    const float* __restrict__ Wih_f, const float* __restrict__ Whh_f,
    const float* __restrict__ bih_f, const float* __restrict__ bhh_f,
    const float* __restrict__ Wih_b, const float* __restrict__ Whh_b,
    const float* __restrict__ bih_b, const float* __restrict__ bhh_b,
    f16* __restrict__ h0b /* [B, T, 2H] f16 */)
{
    const int g = blockIdx.x, dir = blockIdx.y;
    const int tid = threadIdx.x;
    const int lane = tid & 63, w = tid >> 6;
    const int q = lane >> 4, n = lane & 15;
    const int seq0 = g * GQ;

    const float* Wih = dir ? Wih_b : Wih_f;
    const float* Whh = dir ? Whh_b : Whh_f;
    const float* bih = dir ? bih_b : bih_f;
    const float* bhh = dir ? bhh_b : bhh_f;

    __shared__ int Ls[GQ];
    __shared__ __align__(16) float xst0[8][GQ][4];   // staged x rows (fp32)
    __shared__ __align__(16) f16 ring[16][GQ][72];   // h history ring (pad 72)
    __shared__ __align__(16) f16 hx[2][GQ][72];      // parity h exchange

    if (tid < GQ) Ls[tid] = lengths[seq0 + tid];
    for (int i = tid; i < 2 * GQ * 72; i += 256) ((f16*)hx)[i] = (f16)0.f;
    __syncthreads();
    int maxL = 0;
    #pragma unroll
    for (int i2 = 0; i2 < GQ; i2++) maxL = max(maxL, Ls[i2]);

    // stationary A-frags (weights) + per-lane bias (i,f,g,o of h-index j)
    f16x8 afr[4][2], afx[4];
    f32x4 bias4[4];
    #pragma unroll
    for (int i = 0; i < 4; i++) {
        const int R = 64*w + 16*i + n;
        const int sr = (R & 3) * H + (R >> 2);
        const float4* ph = (const float4*)(Whh + (size_t)sr * H);
        afr[i][0] = cvt8(ph[2*q],     ph[2*q + 1]);      // k = q*8..q*8+7
        afr[i][1] = cvt8(ph[8 + 2*q], ph[8 + 2*q + 1]);  // k = 32+q*8..
        f16x8 a2 = zero8();
        if (q == 0) {   // k=64..67 carry Wih (DIN=4); rest of frag zero
            const float4 wv = *(const float4*)(Wih + (size_t)sr * DIN);
            a2[0]=(f16)wv.x; a2[1]=(f16)wv.y; a2[2]=(f16)wv.z; a2[3]=(f16)wv.w;
        }
        afx[i] = a2;
        const int j = 16*w + 4*i + q;
        bias4[i].x = bih[j]       + bhh[j];
        bias4[i].y = bih[H + j]   + bhh[H + j];
        bias4[i].z = bih[2*H + j] + bhh[2*H + j];
        bias4[i].w = bih[3*H + j] + bhh[3*H + j];
    }

    auto stage0 = [&](int s1) {   // stage 8 x-rows per seq (handles reversal)
        if (tid < 128) {
            const int sl = tid >> 4, sq = tid & 15;
            const int ss = s1 + sl;
            int t = dir ? (Ls[sq] - 1 - ss) : ss;
            if (t < 0) t = 0;
            if (t >= TMAX) t = TMAX - 1;
            *(float4*)&xst0[sl][sq][0] =
                *(const float4*)(x + ((size_t)(seq0 + sq) * TMAX + t) * DIN);
        }
    };

    stage0(0);
    __syncthreads();

    f16x8 hb0 = *(const f16x8*)&hx[0][n][q*8];
    f16x8 hb1 = *(const f16x8*)&hx[0][n][32 + q*8];
    f16x8 xb = zero8();
    if (q == 0) {
        float4 xv = *(const float4*)&xst0[0][n][0];
        xb[0]=(f16)xv.x; xb[1]=(f16)xv.y; xb[2]=(f16)xv.z; xb[3]=(f16)xv.w;
    }
    float cst[4] = {0.f, 0.f, 0.f, 0.f};

    for (int s = 0; s < maxL; s++) {
        f32x4 acc[4];
        #pragma unroll
        for (int i = 0; i < 4; i++) {
            f32x4 a = bias4[i];
            a = MFMA16(afx[i],    xb,  a);
            a = MFMA16(afr[i][0], hb0, a);
            a = MFMA16(afr[i][1], hb1, a);
            acc[i] = a;
        }
        const int pnext = (s + 1) & 1;
        #pragma unroll
        for (int i = 0; i < 4; i++) {
            const float gi = sigmoidf_(acc[i].x);
            const float gf = sigmoidf_(acc[i].y);
            const float gg = tanhf_(acc[i].z);
            const float go = sigmoidf_(acc[i].w);
            cst[i] = fmaf(gf, cst[i], gi * gg);
            const float h = go * tanhf_(cst[i]);
            const f16 hh = (f16)h;
            const int j = 16*w + 4*i + q;
            hx[pnext][n][j] = hh;       // next step's B-frag source
            ring[s & 15][n][j] = hh;    // history for bulk flush
        }
        __syncthreads();                // the ONE per-step barrier
        if ((s & 7) == 7 || s == maxL - 1) {   // bulk h0 flush, masked per seq
            const int sfirst = s & ~7;
            const int nsl = s - sfirst + 1;
            for (int i = tid; i < nsl * GQ * 8; i += 256) {
                const int k8 = i & 7, sq = (i >> 3) & 15, sl = i >> 7;
                const int ss = sfirst + sl;
                if (ss < Ls[sq]) {
                    const int t = dir ? (Ls[sq] - 1 - ss) : ss;
                    f16x8 v = *(const f16x8*)&ring[ss & 15][sq][k8 * 8];
                    *(f16x8*)(h0b + ((size_t)(seq0 + sq) * TMAX + t) * (2*H)
                              + dir * H + k8 * 8) = v;
                }
            }
        }
        if (s + 1 < maxL) {
            if (((s + 1) & 7) == 0) { stage0(s + 1); __syncthreads(); }
            hb0 = *(const f16x8*)&hx[pnext][n][q*8];
            hb1 = *(const f16x8*)&hx[pnext][n][32 + q*8];
            xb = zero8();
            if (q == 0) {
                float4 xv = *(const float4*)&xst0[(s + 1) & 7][n][0];
                xb[0]=(f16)xv.x; xb[1]=(f16)xv.y; xb[2]=(f16)xv.z; xb[3]=(f16)xv.w;
            }
        }
    }
}

// ============ Layer 1 forward: MFMA, K = 64(h) + 128(h0 row) = 192 ==========
__global__ __launch_bounds__(256) void lstm1_mfma(
    const f16* __restrict__ h0b, const int* __restrict__ lengths,
    const float* __restrict__ Wih, const float* __restrict__ Whh,
    const float* __restrict__ bih, const float* __restrict__ bhh,
    float* __restrict__ ylast /* [B, H] fp32: h_fwd at L-1 */)
{
    const int g = blockIdx.x;
    const int tid = threadIdx.x;
    const int lane = tid & 63, w = tid >> 6;
    const int q = lane >> 4, n = lane & 15;
    const int seq0 = g * GQ;

    __shared__ int Ls[GQ];
    __shared__ __align__(16) f16 xst[8][GQ][136];  // staged h0 rows (pad 136)
    __shared__ __align__(16) f16 hx[2][GQ][72];

    if (tid < GQ) Ls[tid] = lengths[seq0 + tid];
    for (int i = tid; i < 2 * GQ * 72; i += 256) ((f16*)hx)[i] = (f16)0.f;
    __syncthreads();
    int maxL = 0;
    #pragma unroll
    for (int i2 = 0; i2 < GQ; i2++) maxL = max(maxL, Ls[i2]);
    const int Lme = Ls[n];

    f16x8 afr[4][6];
    f32x4 bias4[4];
    #pragma unroll
    for (int i = 0; i < 4; i++) {
        const int R = 64*w + 16*i + n;
        const int sr = (R & 3) * H + (R >> 2);
        const float4* ph = (const float4*)(Whh + (size_t)sr * H);
        afr[i][0] = cvt8(ph[2*q],     ph[2*q + 1]);
        afr[i][1] = cvt8(ph[8 + 2*q], ph[8 + 2*q + 1]);
        const float4* pxw = (const float4*)(Wih + (size_t)sr * (2*H));
        #pragma unroll
        for (int f = 0; f < 4; f++)
            afr[i][2 + f] = cvt8(pxw[f*8 + 2*q], pxw[f*8 + 2*q + 1]);
        const int j = 16*w + 4*i + q;
        bias4[i].x = bih[j]       + bhh[j];
        bias4[i].y = bih[H + j]   + bhh[H + j];
        bias4[i].z = bih[2*H + j] + bhh[2*H + j];
        bias4[i].w = bih[3*H + j] + bhh[3*H + j];
    }

    auto stage1 = [&](int s1) {   // 8 h0 rows x 16 seqs, 16B granules
        #pragma unroll
        for (int it = 0; it < 8; it++) {
            const int i = tid + 256 * it;
            const int k8 = i & 15, sq = (i >> 4) & 15, sl = i >> 8;
            int t = s1 + sl;
            if (t >= TMAX) t = TMAX - 1;
            f16x8 v = *(const f16x8*)(h0b + ((size_t)(seq0 + sq) * TMAX + t) * (2*H) + k8 * 8);
            *(f16x8*)&xst[sl][sq][k8 * 8] = v;
        }
    };

    stage1(0);
    __syncthreads();

    f16x8 hb0 = *(const f16x8*)&hx[0][n][q*8];
    f16x8 hb1 = *(const f16x8*)&hx[0][n][32 + q*8];
    f16x8 xb[4];
    #pragma unroll
    for (int f = 0; f < 4; f++)
        xb[f] = *(const f16x8*)&xst[0][n][f*32 + q*8];

    float cst[4]   = {0.f, 0.f, 0.f, 0.f};
    float hlast[4] = {0.f, 0.f, 0.f, 0.f};

    for (int s = 0; s < maxL; s++) {
        f32x4 acc[4];
        #pragma unroll
        for (int i = 0; i < 4; i++) {
            f32x4 a = bias4[i];
            a = MFMA16(afr[i][2], xb[0], a);   // x-part first (prefetched)
            a = MFMA16(afr[i][3], xb[1], a);
            a = MFMA16(afr[i][4], xb[2], a);
            a = MFMA16(afr[i][5], xb[3], a);
            a = MFMA16(afr[i][0], hb0, a);     // serial h-part last
            a = MFMA16(afr[i][1], hb1, a);
            acc[i] = a;
        }
        const int pnext = (s + 1) & 1;
        const bool snap = (s == Lme - 1);      // per-lane (seq = n) predicate
        #pragma unroll
        for (int i = 0; i < 4; i++) {
            const float gi = sigmoidf_(acc[i].x);
            const float gf = sigmoidf_(acc[i].y);
            const float gg = tanhf_(acc[i].z);
            const float go = sigmoidf_(acc[i].w);
            cst[i] = fmaf(gf, cst[i], gi * gg);
            const float h = go * tanhf_(cst[i]);
            if (snap) hlast[i] = h;
            hx[pnext][n][16*w + 4*i + q] = (f16)h;
        }
        __syncthreads();
        if (s + 1 < maxL) {
            const int sl = (s + 1) & 7;
            if (sl == 0) { stage1(s + 1); __syncthreads(); }
            hb0 = *(const f16x8*)&hx[pnext][n][q*8];
            hb1 = *(const f16x8*)&hx[pnext][n][32 + q*8];
            #pragma unroll
            for (int f = 0; f < 4; f++)
                xb[f] = *(const f16x8*)&xst[sl][n][f*32 + q*8];
        }
    }
    #pragma unroll
    for (int i = 0; i < 4; i++)
        ylast[(size_t)(seq0 + n) * H + 16*w + 4*i + q] = hlast[i];
}

// ====== Epilogue (per seq): bwd first step (zero state -> Whh_l1b unused) ===
// + logits. VALU, 512 parallel blocks — proven structure from R8.
__global__ __launch_bounds__(256) void epi_kernel(
    const f16* __restrict__ h0b, const float* __restrict__ ylast,
    const int* __restrict__ lengths,
    const float* __restrict__ Wih_b,
    const float* __restrict__ bih_b, const float* __restrict__ bhh_b,
    const float* __restrict__ Wout, const float* __restrict__ bout,
    float* __restrict__ out)
{
    const int b = blockIdx.x;
    const int t = threadIdx.x;
    const int L = lengths[b];
    __shared__ __align__(16) float y[2*H];
    __shared__ __align__(16) float xrow[2*H];
    __shared__ float gb[256];

    if (t < 2*H) xrow[t] = (float)h0b[((size_t)b * TMAX + (L - 1)) * (2*H) + t];
    if (t < H)   y[t] = ylast[(size_t)b * H + t];
    __syncthreads();
    {
        float a0 = bih_b[t] + bhh_b[t], a1 = 0.f, a2 = 0.f, a3 = 0.f;
        const float4* wr = (const float4*)(Wih_b + (size_t)t * (2*H));
        const float4* xv = (const float4*)xrow;
        #pragma unroll
        for (int k = 0; k < 32; k++) {
            float4 wv = wr[k], xk = xv[k];
            a0 = fmaf(wv.x, xk.x, a0); a1 = fmaf(wv.y, xk.y, a1);
            a2 = fmaf(wv.z, xk.z, a2); a3 = fmaf(wv.w, xk.w, a3);
        }
        const float a = (a0 + a1) + (a2 + a3);
        gb[t] = (t >= 128 && t < 192) ? tanhf_(a) : sigmoidf_(a);
    }
    __syncthreads();
    if (t < H) {
        const float cb = gb[t] * gb[128 + t];   // c_prev = 0, f unused
        y[H + t] = gb[192 + t] * tanhf_(cb);
    }
    __syncthreads();

    const float4* yv = (const float4*)y;
    for (int o = t; o < NC; o += 256) {
        float a0 = bout[o], a1 = 0.f, a2 = 0.f, a3 = 0.f;
        const float4* wr = (const float4*)(Wout + (size_t)o * (2*H));
        #pragma unroll
        for (int k = 0; k < 32; k++) {
            float4 wv = wr[k], yy = yv[k];
            a0 = fmaf(wv.x, yy.x, a0); a1 = fmaf(wv.y, yy.y, a1);
            a2 = fmaf(wv.z, yy.z, a2); a3 = fmaf(wv.w, yy.w, a3);
        }
        out[(size_t)b * NC + o] = (a0 + a1) + (a2 + a3);
    }
}

extern "C" void kernel_launch(void* const* d_in, const int* in_sizes, int n_in,
                              void* d_out, int out_size, void* d_ws, size_t ws_size,
                              hipStream_t stream) {
    const float* x        = (const float*)d_in[0];
    const int*   lengths  = (const int*)  d_in[1];
    const float* Wih_l0f  = (const float*)d_in[2];
    const float* Whh_l0f  = (const float*)d_in[3];
    const float* bih_l0f  = (const float*)d_in[4];
    const float* bhh_l0f  = (const float*)d_in[5];
    const float* Wih_l0b  = (const float*)d_in[6];
    const float* Whh_l0b  = (const float*)d_in[7];
    const float* bih_l0b  = (const float*)d_in[8];
    const float* bhh_l0b  = (const float*)d_in[9];
    const float* Wih_l1f  = (const float*)d_in[10];
    const float* Whh_l1f  = (const float*)d_in[11];
    const float* bih_l1f  = (const float*)d_in[12];
    const float* bhh_l1f  = (const float*)d_in[13];
    const float* Wih_l1b  = (const float*)d_in[14];
    // d_in[15] = Whh_l1b: unused (backward dir only needs its first step, h=0)
    const float* bih_l1b  = (const float*)d_in[16];
    const float* bhh_l1b  = (const float*)d_in[17];
    const float* Wout     = (const float*)d_in[18];
    const float* bout     = (const float*)d_in[19];
    float* out = (float*)d_out;

    // ws: h0 f16 [B,T,2H] = 128 MiB ; ylast fp32 [B,H] = 128 KiB
    f16*   h0b   = (f16*)d_ws;
    float* ylast = (float*)((char*)d_ws + (size_t)BATCH * TMAX * (2*H) * sizeof(f16));

    lstm0_mfma<<<dim3(BATCH / GQ, 2), 256, 0, stream>>>(
        x, lengths,
        Wih_l0f, Whh_l0f, bih_l0f, bhh_l0f,
        Wih_l0b, Whh_l0b, bih_l0b, bhh_l0b, h0b);

    lstm1_mfma<<<dim3(BATCH / GQ), 256, 0, stream>>>(
        h0b, lengths, Wih_l1f, Whh_l1f, bih_l1f, bhh_l1f, ylast);

    epi_kernel<<<dim3(BATCH), 256, 0, stream>>>(
        h0b, ylast, lengths,
        Wih_l1b, bih_l1b, bhh_l1b, Wout, bout, out);
}